// Round 1
// baseline (2837.448 us; speedup 1.0000x reference)
//
#include <hip/hip_runtime.h>
#include <math.h>

constexpr int S  = 4096;
constexpr int DM = 2048;
constexpr int H  = 8;
constexpr int KV = 4;
constexpr int DH = 256;
constexpr int WIN = 1024;

constexpr int QT = 32;   // query tile per attention block
constexpr int KT = 16;   // key tile per attention block

// ---------------------------------------------------------------------------
// GEMM fp32: C[M,N] = A[M,K] * B[K,N]   (row-major, M%128==0, N%128==0, K%8==0)
// 128x128 block tile, 256 threads, 8x8 per-thread tile (split +0/+64 layout)
// ---------------------------------------------------------------------------
__global__ __launch_bounds__(256) void gemm_f32(
    const float* __restrict__ A, const float* __restrict__ B,
    float* __restrict__ C, int M, int N, int K) {
  __shared__ float As[8][128];   // transposed A tile: As[k][m]
  __shared__ float Bs[8][128];   // Bs[k][n]
  const int tid  = threadIdx.x;
  const int bm   = blockIdx.y * 128;
  const int bn   = blockIdx.x * 128;
  const int arow = tid >> 1;            // 0..127
  const int acol = (tid & 1) << 2;      // 0 or 4
  const int brow = tid >> 5;            // 0..7
  const int bcol = (tid & 31) << 2;     // 0..124
  const int tx   = tid & 15;
  const int ty   = tid >> 4;

  const float* Ap = A + (size_t)(bm + arow) * K + acol;
  const float* Bp = B + (size_t)brow * N + bn + bcol;

  float acc[8][8];
#pragma unroll
  for (int i = 0; i < 8; ++i)
#pragma unroll
    for (int j = 0; j < 8; ++j) acc[i][j] = 0.f;

  for (int k0 = 0; k0 < K; k0 += 8) {
    const float4 av = *(const float4*)(Ap + k0);
    const float4 bv = *(const float4*)(Bp + (size_t)k0 * N);
    __syncthreads();
    As[acol + 0][arow] = av.x;
    As[acol + 1][arow] = av.y;
    As[acol + 2][arow] = av.z;
    As[acol + 3][arow] = av.w;
    *(float4*)&Bs[brow][bcol] = bv;
    __syncthreads();
#pragma unroll
    for (int kk = 0; kk < 8; ++kk) {
      const float4 a0 = *(const float4*)&As[kk][ty * 4];
      const float4 a1 = *(const float4*)&As[kk][64 + ty * 4];
      const float4 b0 = *(const float4*)&Bs[kk][tx * 4];
      const float4 b1 = *(const float4*)&Bs[kk][64 + tx * 4];
      const float ar[8] = {a0.x, a0.y, a0.z, a0.w, a1.x, a1.y, a1.z, a1.w};
      const float br[8] = {b0.x, b0.y, b0.z, b0.w, b1.x, b1.y, b1.z, b1.w};
#pragma unroll
      for (int i = 0; i < 8; ++i)
#pragma unroll
        for (int j = 0; j < 8; ++j) acc[i][j] += ar[i] * br[j];
    }
  }
#pragma unroll
  for (int i = 0; i < 8; ++i) {
    const int r = bm + ((i < 4) ? (ty * 4 + i) : (64 + ty * 4 + (i - 4)));
    const float4 c0 = make_float4(acc[i][0], acc[i][1], acc[i][2], acc[i][3]);
    const float4 c1 = make_float4(acc[i][4], acc[i][5], acc[i][6], acc[i][7]);
    *(float4*)&C[(size_t)r * N + bn + tx * 4] = c0;
    *(float4*)&C[(size_t)r * N + bn + 64 + tx * 4] = c1;
  }
}

// ---------------------------------------------------------------------------
// Fused RMSNorm (+ optional weight) + RoPE.
// grid = (S, H + KV + KV); block = 256 (one thread per dim of DH=256)
// slot < H        : q head  (norm * q_norm_w, rope)
// slot < H+KV     : k head  (norm * k_norm_w, rope)
// else            : v head  (norm only, no weight, no rope)
// ---------------------------------------------------------------------------
__global__ __launch_bounds__(256) void norm_rope(
    float* __restrict__ qb, float* __restrict__ kb, float* __restrict__ vb,
    const float* __restrict__ cosb, const float* __restrict__ sinb,
    const float* __restrict__ qw, const float* __restrict__ kw) {
  const int s    = blockIdx.x;
  const int slot = blockIdx.y;
  const int d    = threadIdx.x;

  float* base;
  const float* w = nullptr;
  bool rope = true;
  if (slot < H) {
    base = qb + ((size_t)s * H + slot) * DH;
    w = qw;
  } else if (slot < H + KV) {
    base = kb + ((size_t)s * KV + (slot - H)) * DH;
    w = kw;
  } else {
    base = vb + ((size_t)s * KV + (slot - H - KV)) * DH;
    rope = false;
  }

  const float x = base[d];
  float ss = x * x;
#pragma unroll
  for (int o = 32; o > 0; o >>= 1) ss += __shfl_xor(ss, o, 64);

  __shared__ float red[4];
  __shared__ float yn[DH];
  if ((d & 63) == 0) red[d >> 6] = ss;
  __syncthreads();
  const float tot  = red[0] + red[1] + red[2] + red[3];
  const float rstd = rsqrtf(tot * (1.f / DH) + 1e-6f);
  float y = x * rstd;
  if (w) y *= w[d];

  if (rope) {
    yn[d] = y;
    __syncthreads();
    const float c     = cosb[(size_t)s * DH + d];
    const float sn    = sinb[(size_t)s * DH + d];
    const float other = (d < DH / 2) ? -yn[d + DH / 2] : yn[d - DH / 2];
    y = y * c + other * sn;
  }
  base[d] = y;
}

// ---------------------------------------------------------------------------
// Flash-style attention, fp32, online softmax.
// grid = (S/QT, H); block = 256.
// Score phase: thread (sq=tid>>3, sdg=tid&7); Q fragment (32 floats) in regs,
//   K tile in LDS; 8-lane shuffle reduce for the 256-dim dot.
// PV phase: thread (pq=tid>>5, pd=tid&31) owns a 4q x 8d accumulator block.
// Mask: causal AND (q-k < WIN) AND same doc.
// ---------------------------------------------------------------------------
__global__ __launch_bounds__(256) void attn_fp32(
    const float* __restrict__ Qb, const float* __restrict__ Kb,
    const float* __restrict__ Vb, const int* __restrict__ doc,
    float* __restrict__ Ob) {
  __shared__ float Ks[KT][260];      // padded: stride 260 floats (16B aligned rows)
  __shared__ float Vs[KT][DH];
  __shared__ float Ps[KT][36];       // scores then probabilities, P[k][q]
  __shared__ int   docs[KT];
  __shared__ float mrow[QT], lrow[QT], scal[QT];

  const int tid  = threadIdx.x;
  const int h    = blockIdx.y;
  const int kvh  = h >> 1;           // H/KV == 2
  const int q0   = blockIdx.x * QT;

  // ---- score-phase mapping + Q fragment ----
  const int sq    = tid >> 3;        // 0..31 query row
  const int sdg   = tid & 7;         // 0..7 dim group (owns dims sdg*4 + 32*jj)
  const int qglob = q0 + sq;
  const int myDoc = doc[qglob];
  float4 qf[8];
  {
    const float* qrow = Qb + ((size_t)qglob * H + h) * DH;
#pragma unroll
    for (int jj = 0; jj < 8; ++jj)
      qf[jj] = *(const float4*)(qrow + sdg * 4 + jj * 32);
  }

  // ---- PV mapping + accumulators ----
  const int pq = tid >> 5;           // 0..7  -> q rows pq*4 .. pq*4+3
  const int pd = tid & 31;           // 0..31 -> dims pd*4..+3 and 128+pd*4..+3
  float o[4][8];
#pragma unroll
  for (int i = 0; i < 4; ++i)
#pragma unroll
    for (int j = 0; j < 8; ++j) o[i][j] = 0.f;

  if (tid < QT) { mrow[tid] = -1e30f; lrow[tid] = 0.f; }

  const int klo   = (q0 - (WIN - 1)) > 0 ? (q0 - (WIN - 1)) : 0;
  const int khi   = q0 + QT - 1;
  const int ntile = (khi - klo + KT) / KT;

  for (int t = 0; t < ntile; ++t) {
    const int ks0 = klo + t * KT;
    __syncthreads();   // prior tile's PV reads done before restaging
    // ---- stage K/V tile ----
    for (int i = tid; i < KT * DH / 4; i += 256) {
      const int r  = i >> 6;
      const int d  = (i & 63) << 2;
      const int kg = ks0 + r;
      const int kr = kg < S ? kg : S - 1;
      *(float4*)&Ks[r][d] = *(const float4*)(Kb + ((size_t)kr * KV + kvh) * DH + d);
      *(float4*)&Vs[r][d] = *(const float4*)(Vb + ((size_t)kr * KV + kvh) * DH + d);
    }
    if (tid < KT) {
      const int kg = ks0 + tid;
      docs[tid] = doc[kg < S ? kg : S - 1];
    }
    __syncthreads();
    // ---- scores: S[k][q] ----
    for (int k = 0; k < KT; ++k) {
      float sd = 0.f;
#pragma unroll
      for (int jj = 0; jj < 8; ++jj) {
        const float4 kv = *(const float4*)&Ks[k][sdg * 4 + jj * 32];
        sd += qf[jj].x * kv.x + qf[jj].y * kv.y + qf[jj].z * kv.z + qf[jj].w * kv.w;
      }
      sd += __shfl_xor(sd, 1, 64);
      sd += __shfl_xor(sd, 2, 64);
      sd += __shfl_xor(sd, 4, 64);
      if (sdg == 0) {
        const int kg = ks0 + k;
        const bool valid =
            (kg <= qglob) && (qglob - kg < WIN) && (docs[k] == myDoc);
        Ps[k][sq] = valid ? sd : -1e30f;
      }
    }
    __syncthreads();
    // ---- online softmax update (wave 0, one thread per q row) ----
    if (tid < QT) {
      const int q = tid;
      float tm = -1e30f;
      for (int k = 0; k < KT; ++k) tm = fmaxf(tm, Ps[k][q]);
      const float mo = mrow[q];
      const float mn = fmaxf(mo, tm);
      const float sc = __expf(mo - mn);
      float l = lrow[q] * sc;
      for (int k = 0; k < KT; ++k) {
        const float sv = Ps[k][q];
        const float p  = (sv > -1e29f) ? __expf(sv - mn) : 0.f;
        Ps[k][q] = p;
        l += p;
      }
      mrow[q] = mn;
      lrow[q] = l;
      scal[q] = sc;
    }
    __syncthreads();
    // ---- PV accumulate ----
    {
      const float s0 = scal[pq * 4 + 0];
      const float s1 = scal[pq * 4 + 1];
      const float s2 = scal[pq * 4 + 2];
      const float s3 = scal[pq * 4 + 3];
#pragma unroll
      for (int j = 0; j < 8; ++j) {
        o[0][j] *= s0; o[1][j] *= s1; o[2][j] *= s2; o[3][j] *= s3;
      }
      for (int k = 0; k < KT; ++k) {
        const float4 p4  = *(const float4*)&Ps[k][pq * 4];
        const float4 va  = *(const float4*)&Vs[k][pd * 4];
        const float4 vb2 = *(const float4*)&Vs[k][128 + pd * 4];
        const float pr[4] = {p4.x, p4.y, p4.z, p4.w};
#pragma unroll
        for (int i = 0; i < 4; ++i) {
          o[i][0] += pr[i] * va.x;
          o[i][1] += pr[i] * va.y;
          o[i][2] += pr[i] * va.z;
          o[i][3] += pr[i] * va.w;
          o[i][4] += pr[i] * vb2.x;
          o[i][5] += pr[i] * vb2.y;
          o[i][6] += pr[i] * vb2.z;
          o[i][7] += pr[i] * vb2.w;
        }
      }
    }
  }
  // ---- epilogue: normalize and write attn output (S, H*DH) ----
#pragma unroll
  for (int i = 0; i < 4; ++i) {
    const int q = pq * 4 + i;
    const float inv = 1.f / lrow[q];
    float* orow = Ob + ((size_t)(q0 + q) * H + h) * DH;
    const float4 c0 = make_float4(o[i][0] * inv, o[i][1] * inv,
                                  o[i][2] * inv, o[i][3] * inv);
    const float4 c1 = make_float4(o[i][4] * inv, o[i][5] * inv,
                                  o[i][6] * inv, o[i][7] * inv);
    *(float4*)(orow + pd * 4) = c0;
    *(float4*)(orow + 128 + pd * 4) = c1;
  }
}

// ---------------------------------------------------------------------------
extern "C" void kernel_launch(void* const* d_in, const int* in_sizes, int n_in,
                              void* d_out, int out_size, void* d_ws, size_t ws_size,
                              hipStream_t stream) {
  const float* hidden = (const float*)d_in[0];
  const float* cosb   = (const float*)d_in[1];
  const float* sinb   = (const float*)d_in[2];
  const int*   doc    = (const int*)d_in[3];
  const float* Wq     = (const float*)d_in[4];
  const float* Wk     = (const float*)d_in[5];
  const float* Wv     = (const float*)d_in[6];
  const float* Wo     = (const float*)d_in[7];
  const float* qw     = (const float*)d_in[8];
  const float* kw     = (const float*)d_in[9];
  float* out = (float*)d_out;

  float* ws = (float*)d_ws;
  float* qb = ws;                       // 4096*2048
  float* kb = qb + (size_t)S * H * DH;  // 4096*1024
  float* vb = kb + (size_t)S * KV * DH; // 4096*1024
  float* ab = vb + (size_t)S * KV * DH; // 4096*2048

  const dim3 blk(256);

  // q/k/v projections
  gemm_f32<<<dim3((H * DH) / 128, S / 128), blk, 0, stream>>>(
      hidden, Wq, qb, S, H * DH, DM);
  gemm_f32<<<dim3((KV * DH) / 128, S / 128), blk, 0, stream>>>(
      hidden, Wk, kb, S, KV * DH, DM);
  gemm_f32<<<dim3((KV * DH) / 128, S / 128), blk, 0, stream>>>(
      hidden, Wv, vb, S, KV * DH, DM);

  // fused rmsnorm + rope
  norm_rope<<<dim3(S, H + KV + KV), blk, 0, stream>>>(
      qb, kb, vb, cosb, sinb, qw, kw);

  // attention
  attn_fp32<<<dim3(S / QT, H), blk, 0, stream>>>(qb, kb, vb, doc, ab);

  // output projection
  gemm_f32<<<dim3(DM / 128, S / 128), blk, 0, stream>>>(
      ab, Wo, out, S, DM, DM);
}

// Round 9
// 777.560 us; speedup vs baseline: 3.6492x; 3.6492x over previous
//
#include <hip/hip_runtime.h>
#include <math.h>

constexpr int S  = 4096;
constexpr int DM = 2048;
constexpr int H  = 8;
constexpr int KV = 4;
constexpr int DH = 256;
constexpr int WIN = 1024;

constexpr int AQT = 64;   // queries per attention block (4 waves x 16)
constexpr int AKT = 32;   // keys per attention tile

typedef unsigned int  u32;
typedef unsigned short u16;
typedef __attribute__((ext_vector_type(8))) short bf16x8;
typedef __attribute__((ext_vector_type(4))) float f32x4;

__device__ inline u16 f2bf(float f) {
  u32 u = __float_as_uint(f);
  u32 r = u + 0x7FFFu + ((u >> 16) & 1u);   // round-to-nearest-even
  return (u16)(r >> 16);
}
__device__ inline float bf2f(u16 h) { return __uint_as_float((u32)h << 16); }

// ---------------------------------------------------------------------------
// split fp32 -> bf16 hi (+ optional lo = rne(x - hi))
// ---------------------------------------------------------------------------
__global__ __launch_bounds__(256) void split_f32(
    const float* __restrict__ x, u16* __restrict__ hi, u16* __restrict__ lo,
    int n4) {
  const int i = blockIdx.x * 256 + threadIdx.x;
  if (i >= n4) return;
  const float4 v = *(const float4*)(x + (size_t)i * 4);
  ushort4 h;
  h.x = f2bf(v.x); h.y = f2bf(v.y); h.z = f2bf(v.z); h.w = f2bf(v.w);
  *(ushort4*)(hi + (size_t)i * 4) = h;
  if (lo) {
    ushort4 l;
    l.x = f2bf(v.x - bf2f(h.x));
    l.y = f2bf(v.y - bf2f(h.y));
    l.z = f2bf(v.z - bf2f(h.z));
    l.w = f2bf(v.w - bf2f(h.w));
    *(ushort4*)(lo + (size_t)i * 4) = l;
  }
}

// ---------------------------------------------------------------------------
// transpose + split: W (K,N) fp32 -> Thi/Tlo (N,K) bf16.  64x64 tiles.
// ---------------------------------------------------------------------------
__global__ __launch_bounds__(256) void tsplit(
    const float* __restrict__ W, u16* __restrict__ Thi, u16* __restrict__ Tlo,
    int K, int N) {
  __shared__ float t[64][65];
  const int k0 = blockIdx.x * 64, n0 = blockIdx.y * 64;
  const int tid = threadIdx.x;
  const int r  = tid >> 4;
  const int c4 = (tid & 15) * 4;
#pragma unroll
  for (int p = 0; p < 4; ++p) {
    const float4 v = *(const float4*)&W[(size_t)(k0 + p * 16 + r) * N + n0 + c4];
    t[p * 16 + r][c4 + 0] = v.x;
    t[p * 16 + r][c4 + 1] = v.y;
    t[p * 16 + r][c4 + 2] = v.z;
    t[p * 16 + r][c4 + 3] = v.w;
  }
  __syncthreads();
#pragma unroll
  for (int p = 0; p < 4; ++p) {
    const int n = p * 16 + r;
    float x0 = t[c4 + 0][n], x1 = t[c4 + 1][n];
    float x2 = t[c4 + 2][n], x3 = t[c4 + 3][n];
    ushort4 h, l;
    h.x = f2bf(x0); h.y = f2bf(x1); h.z = f2bf(x2); h.w = f2bf(x3);
    l.x = f2bf(x0 - bf2f(h.x));
    l.y = f2bf(x1 - bf2f(h.y));
    l.z = f2bf(x2 - bf2f(h.z));
    l.w = f2bf(x3 - bf2f(h.w));
    *(ushort4*)&Thi[(size_t)(n0 + n) * K + k0 + c4] = h;
    *(ushort4*)&Tlo[(size_t)(n0 + n) * K + k0 + c4] = l;
  }
}

// ---------------------------------------------------------------------------
// MFMA GEMM: C[M,N] f32 = A*B. A (M,K) bf16 hi/lo, Bt (N,K) bf16 hi/lo.
// SPLIT: C = Ahi*Bhi + Ahi*Blo + Alo*Bhi.  128x128 tile, BK=64, 4 waves.
// ---------------------------------------------------------------------------
template <bool SPLIT>
__global__ __launch_bounds__(256) void gemm_mfma(
    const u16* __restrict__ Ahi, const u16* __restrict__ Alo,
    const u16* __restrict__ Bhi, const u16* __restrict__ Blo,
    float* __restrict__ C, int M, int N, int K) {
  __shared__ u16 As_hi[128 * 64];
  __shared__ u16 Bs_hi[128 * 64];
  __shared__ u16 As_lo[SPLIT ? 128 * 64 : 1];
  __shared__ u16 Bs_lo[SPLIT ? 128 * 64 : 1];

  const int tid  = threadIdx.x;
  const int lane = tid & 63;
  const int w    = tid >> 6;
  const int bm   = blockIdx.y * 128;
  const int bn   = blockIdx.x * 128;
  const int wm   = (w & 1) * 64;
  const int wn   = (w >> 1) * 64;
  const int fr   = lane & 15;
  const int fq   = lane >> 4;

  const int sr = tid >> 3;
  const int sc = tid & 7;

  f32x4 acc[4][4];
#pragma unroll
  for (int i = 0; i < 4; ++i)
#pragma unroll
    for (int j = 0; j < 4; ++j) acc[i][j] = (f32x4){0.f, 0.f, 0.f, 0.f};

  for (int k0 = 0; k0 < K; k0 += 64) {
    __syncthreads();
#pragma unroll
    for (int p = 0; p < 4; ++p) {
      const int r  = p * 32 + sr;
      const int cs = sc ^ (r & 7);
      const size_t ga = (size_t)(bm + r) * K + k0 + sc * 8;
      const size_t gb = (size_t)(bn + r) * K + k0 + sc * 8;
      const uint4 va = *(const uint4*)(Ahi + ga);
      const uint4 vb = *(const uint4*)(Bhi + gb);
      *(uint4*)((char*)As_hi + r * 128 + cs * 16) = va;
      *(uint4*)((char*)Bs_hi + r * 128 + cs * 16) = vb;
      if constexpr (SPLIT) {
        const uint4 va2 = *(const uint4*)(Alo + ga);
        const uint4 vb2 = *(const uint4*)(Blo + gb);
        *(uint4*)((char*)As_lo + r * 128 + cs * 16) = va2;
        *(uint4*)((char*)Bs_lo + r * 128 + cs * 16) = vb2;
      }
    }
    __syncthreads();
#pragma unroll
    for (int ks = 0; ks < 2; ++ks) {
      const int chunk = ks * 4 + fq;
      bf16x8 ah[4], bh[4], al[4], bl[4];
#pragma unroll
      for (int mt = 0; mt < 4; ++mt) {
        const int row = wm + mt * 16 + fr;
        const int cs  = chunk ^ (row & 7);
        ah[mt] = *(const bf16x8*)((const char*)As_hi + row * 128 + cs * 16);
        if constexpr (SPLIT)
          al[mt] = *(const bf16x8*)((const char*)As_lo + row * 128 + cs * 16);
      }
#pragma unroll
      for (int nt = 0; nt < 4; ++nt) {
        const int row = wn + nt * 16 + fr;
        const int cs  = chunk ^ (row & 7);
        bh[nt] = *(const bf16x8*)((const char*)Bs_hi + row * 128 + cs * 16);
        if constexpr (SPLIT)
          bl[nt] = *(const bf16x8*)((const char*)Bs_lo + row * 128 + cs * 16);
      }
#pragma unroll
      for (int mt = 0; mt < 4; ++mt)
#pragma unroll
        for (int nt = 0; nt < 4; ++nt) {
          acc[mt][nt] = __builtin_amdgcn_mfma_f32_16x16x32_bf16(
              ah[mt], bh[nt], acc[mt][nt], 0, 0, 0);
          if constexpr (SPLIT) {
            acc[mt][nt] = __builtin_amdgcn_mfma_f32_16x16x32_bf16(
                ah[mt], bl[nt], acc[mt][nt], 0, 0, 0);
            acc[mt][nt] = __builtin_amdgcn_mfma_f32_16x16x32_bf16(
                al[mt], bh[nt], acc[mt][nt], 0, 0, 0);
          }
        }
    }
  }
#pragma unroll
  for (int mt = 0; mt < 4; ++mt)
#pragma unroll
    for (int nt = 0; nt < 4; ++nt) {
      const int gm = bm + wm + mt * 16 + fq * 4;
      const int gn = bn + wn + nt * 16 + fr;
#pragma unroll
      for (int r = 0; r < 4; ++r)
        C[(size_t)(gm + r) * N + gn] = acc[mt][nt][r];
    }
}

// ---------------------------------------------------------------------------
// RMSNorm + weight + RoPE, output split to bf16 hi/lo.  grid (S, nh).
// ---------------------------------------------------------------------------
__global__ __launch_bounds__(256) void norm_rope_qk(
    const float* __restrict__ src, u16* __restrict__ hi, u16* __restrict__ lo,
    const float* __restrict__ w, const float* __restrict__ cosb,
    const float* __restrict__ sinb, int nh) {
  const int s = blockIdx.x, hh = blockIdx.y, d = threadIdx.x;
  const size_t base = ((size_t)s * nh + hh) * DH;
  const float x = src[base + d];
  float ss = x * x;
#pragma unroll
  for (int o = 32; o > 0; o >>= 1) ss += __shfl_xor(ss, o, 64);
  __shared__ float red[4];
  __shared__ float yn[DH];
  if ((d & 63) == 0) red[d >> 6] = ss;
  __syncthreads();
  const float tot  = red[0] + red[1] + red[2] + red[3];
  const float rstd = rsqrtf(tot * (1.f / DH) + 1e-6f);
  float y = x * rstd * w[d];
  yn[d] = y;
  __syncthreads();
  const float c     = cosb[(size_t)s * DH + d];
  const float sn    = sinb[(size_t)s * DH + d];
  const float other = (d < DH / 2) ? -yn[d + DH / 2] : yn[d - DH / 2];
  y = y * c + other * sn;
  const u16 hb = f2bf(y);
  hi[base + d] = hb;
  lo[base + d] = f2bf(y - bf2f(hb));
}

// ---------------------------------------------------------------------------
// RMSNorm (no weight, no rope), in-place f32.  grid (S, KV).
// ---------------------------------------------------------------------------
__global__ __launch_bounds__(256) void norm_v(float* __restrict__ vb) {
  const int s = blockIdx.x, kv = blockIdx.y, d = threadIdx.x;
  float* base = vb + ((size_t)s * KV + kv) * DH;
  const float x = base[d];
  float ss = x * x;
#pragma unroll
  for (int o = 32; o > 0; o >>= 1) ss += __shfl_xor(ss, o, 64);
  __shared__ float red[4];
  if ((d & 63) == 0) red[d >> 6] = ss;
  __syncthreads();
  const float tot  = red[0] + red[1] + red[2] + red[3];
  const float rstd = rsqrtf(tot * (1.f / DH) + 1e-6f);
  base[d] = x * rstd;
}

// ---------------------------------------------------------------------------
// V transpose: vb f32 (S, KV, DH) -> vt bf16 [KV][DH][S].  64x64 tiles.
// grid (S/64, DH/64, KV)
// ---------------------------------------------------------------------------
__global__ __launch_bounds__(256) void vtrans(
    const float* __restrict__ vb, u16* __restrict__ vt) {
  __shared__ float t[64][65];
  const int s0 = blockIdx.x * 64, d0 = blockIdx.y * 64, kv = blockIdx.z;
  const int tid = threadIdx.x;
  const int r  = tid >> 4;
  const int c4 = (tid & 15) * 4;
#pragma unroll
  for (int p = 0; p < 4; ++p) {
    const float4 v =
        *(const float4*)&vb[((size_t)(s0 + p * 16 + r) * KV + kv) * DH + d0 + c4];
    t[p * 16 + r][c4 + 0] = v.x;
    t[p * 16 + r][c4 + 1] = v.y;
    t[p * 16 + r][c4 + 2] = v.z;
    t[p * 16 + r][c4 + 3] = v.w;
  }
  __syncthreads();
#pragma unroll
  for (int p = 0; p < 4; ++p) {
    const int d = p * 16 + r;
    ushort4 h;
    h.x = f2bf(t[c4 + 0][d]);
    h.y = f2bf(t[c4 + 1][d]);
    h.z = f2bf(t[c4 + 2][d]);
    h.w = f2bf(t[c4 + 3][d]);
    *(ushort4*)&vt[((size_t)kv * DH + d0 + d) * S + s0 + c4] = h;
  }
}

// ---------------------------------------------------------------------------
// MFMA flash attention.
// grid (S/AQT, H), 256 threads = 4 waves x 16 queries.
// QK^T: mfma(Q, K) with hi/lo split (3 mfma) -> fp32-grade scores.
// D tile: col=lane&15=key, row=(lane>>4)*4+reg=query.
// Softmax: shfl_xor reduce over fr lanes; state m[4], l[4] per lane.
// P -> bf16 pairs -> per-wave LDS (stride 40 u16); PV: mfma(P, Vt rows).
// ---------------------------------------------------------------------------
__global__ __launch_bounds__(256) void attn_mfma(
    const u16* __restrict__ qhi, const u16* __restrict__ qlo,
    const u16* __restrict__ khi, const u16* __restrict__ klo,
    const u16* __restrict__ vt,  const int* __restrict__ doc,
    u16* __restrict__ ob) {
  __shared__ u16 Ksh[AKT * DH];       // 32 rows x 512B, 16B-chunk XOR swizzle
  __shared__ u16 Ksl[AKT * DH];
  __shared__ u16 Vts[DH * AKT];       // 256 rows x 64B
  __shared__ u16 Psm[4][16 * 40];     // per-wave P, row stride 40 u16 (80B)
  __shared__ int docs[AKT];

  const int tid = threadIdx.x, lane = tid & 63, w = tid >> 6;
  const int fr = lane & 15, fq = lane >> 4;
  const int h = blockIdx.y, kvh = h >> 1;
  const int q0 = blockIdx.x * AQT, qw = q0 + w * 16;

  // Q fragments: 8 K-chunks x (hi,lo); lane(fr,fq) holds Q[qw+fr][c*32+fq*8+j]
  bf16x8 qfh[8], qfl[8];
  {
    const u16* qrh = qhi + ((size_t)(qw + fr) * H + h) * DH;
    const u16* qrl = qlo + ((size_t)(qw + fr) * H + h) * DH;
#pragma unroll
    for (int c = 0; c < 8; ++c) {
      qfh[c] = *(const bf16x8*)(qrh + c * 32 + fq * 8);
      qfl[c] = *(const bf16x8*)(qrl + c * 32 + fq * 8);
    }
  }
  int qdoc[4];
  float m[4], l[4];
  f32x4 O[16];
#pragma unroll
  for (int r = 0; r < 4; ++r) {
    qdoc[r] = doc[qw + fq * 4 + r];
    m[r] = -1e30f;
    l[r] = 0.f;
  }
#pragma unroll
  for (int nt = 0; nt < 16; ++nt) O[nt] = (f32x4){0.f, 0.f, 0.f, 0.f};

  const int kmin   = (q0 - (WIN - 1)) > 0 ? (q0 - (WIN - 1)) : 0;
  const int kstart = kmin & ~(AKT - 1);
  const int kend   = q0 + AQT;

  for (int ks0 = kstart; ks0 < kend; ks0 += AKT) {
    __syncthreads();
    // ---- stage K (hi/lo, swizzled) + Vt + docs ----
    {
      const int r  = tid >> 3;
      const int cg = (tid & 7) * 4;
      const u16* krh = khi + ((size_t)(ks0 + r) * KV + kvh) * DH + cg * 8;
      const u16* krl = klo + ((size_t)(ks0 + r) * KV + kvh) * DH + cg * 8;
      const u16* vr  = vt + ((size_t)kvh * DH + tid) * S + ks0;
      uint4 kh4[4], kl4[4], vv4[4];
#pragma unroll
      for (int j = 0; j < 4; ++j) {
        kh4[j] = *(const uint4*)(krh + j * 8);
        kl4[j] = *(const uint4*)(krl + j * 8);
        vv4[j] = *(const uint4*)(vr + j * 8);
      }
#pragma unroll
      for (int j = 0; j < 4; ++j) {
        const int cs = (cg + j) ^ (r & 7);
        *(uint4*)((char*)Ksh + r * 512 + cs * 16) = kh4[j];
        *(uint4*)((char*)Ksl + r * 512 + cs * 16) = kl4[j];
        *(uint4*)((char*)Vts + tid * 64 + j * 16) = vv4[j];
      }
      if (tid < AKT) docs[tid] = doc[ks0 + tid];
    }
    __syncthreads();

    // ---- QK^T: two 16-key sub-tiles, split hi/lo ----
    f32x4 sc0 = (f32x4){0.f, 0.f, 0.f, 0.f};
    f32x4 sc1 = (f32x4){0.f, 0.f, 0.f, 0.f};
#pragma unroll
    for (int t = 0; t < 2; ++t) {
      f32x4 s = (f32x4){0.f, 0.f, 0.f, 0.f};
      const int rr = t * 16 + fr;
#pragma unroll
      for (int c2 = 0; c2 < 8; ++c2) {
        const int cs = (c2 * 4 + fq) ^ (rr & 7);
        const bf16x8 kh =
            *(const bf16x8*)((const char*)Ksh + rr * 512 + cs * 16);
        const bf16x8 kl =
            *(const bf16x8*)((const char*)Ksl + rr * 512 + cs * 16);
        s = __builtin_amdgcn_mfma_f32_16x16x32_bf16(qfh[c2], kh, s, 0, 0, 0);
        s = __builtin_amdgcn_mfma_f32_16x16x32_bf16(qfh[c2], kl, s, 0, 0, 0);
        s = __builtin_amdgcn_mfma_f32_16x16x32_bf16(qfl[c2], kh, s, 0, 0, 0);
      }
      if (t == 0) sc0 = s; else sc1 = s;
    }

    // ---- mask + online softmax ----
    float p0[4], p1[4], rs[4];
#pragma unroll
    for (int r = 0; r < 4; ++r) {
      const int q   = qw + fq * 4 + r;
      const int kg0 = ks0 + fr, kg1 = ks0 + 16 + fr;
      const bool v0 = (kg0 <= q) && (q - kg0 < WIN) && (docs[fr] == qdoc[r]);
      const bool v1 = (kg1 <= q) && (q - kg1 < WIN) && (docs[16 + fr] == qdoc[r]);
      const float s0 = v0 ? sc0[r] : -1e30f;
      const float s1 = v1 ? sc1[r] : -1e30f;
      float tm = fmaxf(s0, s1);
      tm = fmaxf(tm, __shfl_xor(tm, 1));
      tm = fmaxf(tm, __shfl_xor(tm, 2));
      tm = fmaxf(tm, __shfl_xor(tm, 4));
      tm = fmaxf(tm, __shfl_xor(tm, 8));
      const float mn = fmaxf(m[r], tm);
      rs[r] = __expf(m[r] - mn);
      p0[r] = (s0 > -1e29f) ? __expf(s0 - mn) : 0.f;
      p1[r] = (s1 > -1e29f) ? __expf(s1 - mn) : 0.f;
      float ps = p0[r] + p1[r];
      ps += __shfl_xor(ps, 1);
      ps += __shfl_xor(ps, 2);
      ps += __shfl_xor(ps, 4);
      ps += __shfl_xor(ps, 8);
      l[r] = l[r] * rs[r] + ps;
      m[r] = mn;
    }
    // rescale O accumulators
#pragma unroll
    for (int nt = 0; nt < 16; ++nt)
#pragma unroll
      for (int r = 0; r < 4; ++r) O[nt][r] *= rs[r];

    // ---- write P (bf16 pairs) to per-wave LDS ----
#pragma unroll
    for (int r = 0; r < 4; ++r) {
      const float e0 = __shfl_xor(p0[r], 1);
      const float e1 = __shfl_xor(p1[r], 1);
      const int q16 = fq * 4 + r;
      if ((fr & 1) == 0) {  // keys (fr, fr+1) of sub-tile 0
        const u32 pk = (u32)f2bf(p0[r]) | ((u32)f2bf(e0) << 16);
        *(u32*)(&Psm[w][q16 * 40 + fr]) = pk;
      } else {              // keys (15+fr, 16+fr) of sub-tile 1
        const u32 pk = (u32)f2bf(e1) | ((u32)f2bf(p1[r]) << 16);
        *(u32*)(&Psm[w][q16 * 40 + 15 + fr]) = pk;
      }
    }

    // ---- PV: O += P * V   (same-wave LDS RAW: DS pipe is in-order) ----
    const bf16x8 pa = *(const bf16x8*)(&Psm[w][fr * 40 + fq * 8]);
#pragma unroll
    for (int nt = 0; nt < 16; ++nt) {
      const bf16x8 vf =
          *(const bf16x8*)((const char*)Vts + (nt * 16 + fr) * 64 + fq * 16);
      O[nt] = __builtin_amdgcn_mfma_f32_16x16x32_bf16(pa, vf, O[nt], 0, 0, 0);
    }
  }

  // ---- epilogue: normalize, write bf16 (S, H*DH) ----
#pragma unroll
  for (int r = 0; r < 4; ++r) {
    const float inv = 1.f / l[r];
    const int q = qw + fq * 4 + r;
#pragma unroll
    for (int nt = 0; nt < 16; ++nt)
      ob[(size_t)q * (H * DH) + h * DH + nt * 16 + fr] = f2bf(O[nt][r] * inv);
  }
}

// ---------------------------------------------------------------------------
extern "C" void kernel_launch(void* const* d_in, const int* in_sizes, int n_in,
                              void* d_out, int out_size, void* d_ws, size_t ws_size,
                              hipStream_t stream) {
  const float* hidden = (const float*)d_in[0];
  const float* cosb   = (const float*)d_in[1];
  const float* sinb   = (const float*)d_in[2];
  const int*   doc    = (const int*)d_in[3];
  const float* Wq     = (const float*)d_in[4];
  const float* Wk     = (const float*)d_in[5];
  const float* Wv     = (const float*)d_in[6];
  const float* Wo     = (const float*)d_in[7];
  const float* qw     = (const float*)d_in[8];
  const float* kw     = (const float*)d_in[9];
  float* out = (float*)d_out;

  char* ws = (char*)d_ws;
  constexpr size_t MB = 1ull << 20;
  // 96 MB high-water plan (offsets MB), stream-ordered aliasing:
  //  hhi 0-16, hlo 16-32 | wtQ 32-48 | qb 48-80
  //  qhi 32-48 (over wtQ), qlo 80-96
  //  wtK 48-56 (over qb), kb 56-72 | khi 48-56, klo 72-80
  //  wtV 56-64 (over kb), vb 16-32 (over hlo)
  //  Vt 0-8 (over hhi) | abhi 16-32 (over vb)
  //  woh 8-16, wol 48-56
  u16*   hhi  = (u16*)(ws + 0 * MB);
  u16*   hlo  = (u16*)(ws + 16 * MB);
  u16*   wtqh = (u16*)(ws + 32 * MB);
  u16*   wtql = (u16*)(ws + 40 * MB);
  float* qb   = (float*)(ws + 48 * MB);
  u16*   qhi_ = (u16*)(ws + 32 * MB);
  u16*   qlo_ = (u16*)(ws + 80 * MB);
  u16*   wtkh = (u16*)(ws + 48 * MB);
  u16*   wtkl = (u16*)(ws + 52 * MB);
  float* kb   = (float*)(ws + 56 * MB);
  u16*   khi_ = (u16*)(ws + 48 * MB);
  u16*   klo_ = (u16*)(ws + 72 * MB);
  u16*   wtvh = (u16*)(ws + 56 * MB);
  u16*   wtvl = (u16*)(ws + 60 * MB);
  float* vb   = (float*)(ws + 16 * MB);
  u16*   vt   = (u16*)(ws + 0 * MB);
  u16*   abhi = (u16*)(ws + 16 * MB);
  u16*   woh  = (u16*)(ws + 8 * MB);
  u16*   wol  = (u16*)(ws + 48 * MB);

  const dim3 blk(256);

  // hidden -> hi/lo bf16
  split_f32<<<dim3(S * DM / 4 / 256), blk, 0, stream>>>(hidden, hhi, hlo, S * DM / 4);

  // q = hidden @ Wq   (split precision)
  tsplit<<<dim3(DM / 64, (H * DH) / 64), blk, 0, stream>>>(Wq, wtqh, wtql, DM, H * DH);
  gemm_mfma<true><<<dim3((H * DH) / 128, S / 128), blk, 0, stream>>>(
      hhi, hlo, wtqh, wtql, qb, S, H * DH, DM);
  norm_rope_qk<<<dim3(S, H), blk, 0, stream>>>(qb, qhi_, qlo_, qw, cosb, sinb, H);

  // k = hidden @ Wk   (split precision)
  tsplit<<<dim3(DM / 64, (KV * DH) / 64), blk, 0, stream>>>(Wk, wtkh, wtkl, DM, KV * DH);
  gemm_mfma<true><<<dim3((KV * DH) / 128, S / 128), blk, 0, stream>>>(
      hhi, hlo, wtkh, wtkl, kb, S, KV * DH, DM);
  norm_rope_qk<<<dim3(S, KV), blk, 0, stream>>>(kb, khi_, klo_, kw, cosb, sinb, KV);

  // v = hidden @ Wv   (plain bf16), norm, transpose
  tsplit<<<dim3(DM / 64, (KV * DH) / 64), blk, 0, stream>>>(Wv, wtvh, wtvl, DM, KV * DH);
  gemm_mfma<false><<<dim3((KV * DH) / 128, S / 128), blk, 0, stream>>>(
      hhi, nullptr, wtvh, nullptr, vb, S, KV * DH, DM);
  norm_v<<<dim3(S, KV), blk, 0, stream>>>(vb);
  vtrans<<<dim3(S / 64, DH / 64, KV), blk, 0, stream>>>(vb, vt);

  // attention -> bf16 (S, H*DH)
  attn_mfma<<<dim3(S / AQT, H), blk, 0, stream>>>(
      qhi_, qlo_, khi_, klo_, vt, doc, abhi);

  // out = attn @ Wo   (plain bf16)
  tsplit<<<dim3((H * DH) / 64, DM / 64), blk, 0, stream>>>(Wo, woh, wol, H * DH, DM);
  gemm_mfma<false><<<dim3(DM / 128, S / 128), blk, 0, stream>>>(
      abhi, nullptr, woh, nullptr, out, S, DM, H * DH);
}